// Round 1
// baseline (147.346 us; speedup 1.0000x reference)
//
#include <hip/hip_runtime.h>

// SSM diagonal scan: h_t = dA ⊙ h_{t-1} + dB * x_t ;  y_t = <C, h_t>
//   dt = exp(log_dt); A = exp(A_log); dA = exp(dt*A); dB = dt*B   (all per [d,n])
// Shapes: x [8,512,2048], A_log/B/C [2048,16], log_dt [2048], out [8,512,2048] f32.
//
// Mapping: each thread owns 4 of the 16 states of one (b,d) pair.
//   65536 threads = 1024 waves = 4 waves/CU -> all 4 SIMDs busy (naive 1-thread-per-pair
//   mapping only fills 1 SIMD/CU and is VALU-issue-bound at ~20us).
// Lanes 4k..4k+3 handle the same (b,d): x load is a 64B line per wave per t (coalesced),
// output dot reduced with a 2-step shfl_xor butterfly, lane sg==0 stores.
// x addresses are scan-independent -> 16-deep register prefetch ring hides load latency
// (only 1 wave/SIMD, so latency must be hidden by ILP, not TLP).

#define SSM_BATCH 8
#define SSM_SEQ 512
#define SSM_D 2048
#define SSM_N 16
#define PF 16

__global__ __launch_bounds__(256) void ssm_scan_kernel(
    const float* __restrict__ x, const float* __restrict__ A_log,
    const float* __restrict__ Bm, const float* __restrict__ Cm,
    const float* __restrict__ log_dt, float* __restrict__ out)
{
    const int tid  = threadIdx.x;
    const int sg   = tid & 3;        // state group: states [4*sg, 4*sg+4)
    const int dloc = tid >> 2;       // 0..63
    const int d    = blockIdx.x * 64 + dloc;
    const int b    = blockIdx.y;
    const int n0   = sg * 4;

    // Per-thread parameters (float4 loads are 16B-aligned: row stride 16 floats)
    const float4 al = *(const float4*)(A_log + d * SSM_N + n0);
    const float4 bv = *(const float4*)(Bm    + d * SSM_N + n0);
    const float4 cv = *(const float4*)(Cm    + d * SSM_N + n0);
    const float  dt = expf(log_dt[d]);

    const float dA0 = expf(dt * expf(al.x));
    const float dA1 = expf(dt * expf(al.y));
    const float dA2 = expf(dt * expf(al.z));
    const float dA3 = expf(dt * expf(al.w));
    const float dB0 = dt * bv.x, dB1 = dt * bv.y, dB2 = dt * bv.z, dB3 = dt * bv.w;

    const float* xp = x   + (size_t)b * SSM_SEQ * SSM_D + d;
    float*       op = out + (size_t)b * SSM_SEQ * SSM_D + d;

    float h0 = 0.f, h1 = 0.f, h2 = 0.f, h3 = 0.f;
    const bool writer = (sg == 0);

    // Prefetch ring: x[t .. t+PF) resident in registers.
    float xbuf[PF];
    #pragma unroll
    for (int i = 0; i < PF; ++i) xbuf[i] = xp[i * SSM_D];

    for (int t = 0; t < SSM_SEQ; t += PF) {
        float xn[PF];
        const int tn = t + PF;
        if (tn < SSM_SEQ) {             // uniform branch
            #pragma unroll
            for (int i = 0; i < PF; ++i) xn[i] = xp[(tn + i) * SSM_D];
        }
        #pragma unroll
        for (int i = 0; i < PF; ++i) {
            const float xv = xbuf[i];
            h0 = fmaf(dA0, h0, dB0 * xv);
            h1 = fmaf(dA1, h1, dB1 * xv);
            h2 = fmaf(dA2, h2, dB2 * xv);
            h3 = fmaf(dA3, h3, dB3 * xv);
            float p = cv.x * h0;
            p = fmaf(cv.y, h1, p);
            p = fmaf(cv.z, h2, p);
            p = fmaf(cv.w, h3, p);
            // butterfly over the 4 state-group lanes
            p += __shfl_xor(p, 1, 64);
            p += __shfl_xor(p, 2, 64);
            if (writer) op[(t + i) * SSM_D] = p;
        }
        #pragma unroll
        for (int i = 0; i < PF; ++i) xbuf[i] = xn[i];
    }
}

extern "C" void kernel_launch(void* const* d_in, const int* in_sizes, int n_in,
                              void* d_out, int out_size, void* d_ws, size_t ws_size,
                              hipStream_t stream) {
    const float* x      = (const float*)d_in[0];
    const float* A_log  = (const float*)d_in[1];
    const float* B      = (const float*)d_in[2];
    const float* C      = (const float*)d_in[3];
    const float* log_dt = (const float*)d_in[4];
    float* out = (float*)d_out;

    dim3 grid(SSM_D / 64, SSM_BATCH);   // 32 x 8 = 256 blocks, 1 block/CU
    ssm_scan_kernel<<<grid, 256, 0, stream>>>(x, A_log, B, C, log_dt, out);
}

// Round 2
// 115.588 us; speedup vs baseline: 1.2748x; 1.2748x over previous
//
#include <hip/hip_runtime.h>
#include <math.h>

// SSM diagonal scan, chunked 2-pass formulation.
//   h_t = dA ⊙ h_{t-1} + dB * x_t ;  y_t = <C, h_t>
//   dt = exp(log_dt); A = exp(A_log); dA = exp(dt*A); dB = dt*B
// Shapes: x [8,512,2048], A_log/B/C [2048,16], log_dt [2048], out [8,512,2048] f32.
//
// Round-1 postmortem: 1 wave/SIMD + per-step dependent shfl_xor pair = latency-
// exposed (VALUBusy 16%, occ 10.5%, 80us). The recurrence is linear, so chunk it:
//   NC=8 chunks of L=64  ->  B*D*NC = 131072 threads = 2048 waves = 8 waves/CU.
// Pass1: per-(b,d,c) thread scans chunk from h=0, stores final local state S_c [16].
// Combine: carry_c = H_{c-1} where H_c = dA^L ⊙ H_{c-1} + S_c (dA^L = exp(L*dt*A)).
// Pass2: per-(b,d,c) thread rescans chunk from carry_c, writes y. No cross-lane ops,
// all 16 states in registers, x/y accesses 4B/lane fully coalesced. x is read twice
// but lives in the 256MB L3, so HBM traffic is ~unchanged.

#define SSM_BATCH 8
#define SSM_SEQ 512
#define SSM_D 2048
#define SSM_N 16
#define PF 8

typedef float float4v __attribute__((ext_vector_type(4)));

static __device__ inline float4v fma4(float4v a, float4v b, float4v c) {
    return (float4v){fmaf(a.x, b.x, c.x), fmaf(a.y, b.y, c.y),
                     fmaf(a.z, b.z, c.z), fmaf(a.w, b.w, c.w)};
}
static __device__ inline float4v exp4(float4v v) {
    return (float4v){expf(v.x), expf(v.y), expf(v.z), expf(v.w)};
}

// ---------------- Pass 1: per-chunk local scan, store final state ----------------
template <int L>
__global__ __launch_bounds__(256) void ssm_pass1(
    const float* __restrict__ x, const float* __restrict__ A_log,
    const float* __restrict__ Bm, const float* __restrict__ log_dt,
    float* __restrict__ S)
{
    const int tid = threadIdx.x;
    const int d   = blockIdx.x * 256 + tid;
    const int c   = blockIdx.y;
    const int b   = blockIdx.z;

    const float dt = expf(log_dt[d]);
    float4v dA[4], dB[4], h[4];
    #pragma unroll
    for (int i = 0; i < 4; ++i) {
        float4v al = *(const float4v*)(A_log + d * SSM_N + 4 * i);
        float4v bv = *(const float4v*)(Bm    + d * SSM_N + 4 * i);
        dA[i] = exp4(dt * exp4(al));
        dB[i] = dt * bv;
        h[i]  = (float4v)0.f;
    }

    const float* xp = x + ((size_t)b * SSM_SEQ + c * L) * SSM_D + d;

    float xbuf[PF];
    #pragma unroll
    for (int i = 0; i < PF; ++i) xbuf[i] = xp[i * SSM_D];

    for (int t = 0; t < L; t += PF) {
        float xn[PF];
        if (t + PF < L) {
            #pragma unroll
            for (int i = 0; i < PF; ++i) xn[i] = xp[(t + PF + i) * SSM_D];
        }
        #pragma unroll
        for (int i = 0; i < PF; ++i) {
            const float xv = xbuf[i];
            #pragma unroll
            for (int j = 0; j < 4; ++j) h[j] = fma4(dA[j], h[j], dB[j] * xv);
        }
        #pragma unroll
        for (int i = 0; i < PF; ++i) xbuf[i] = xn[i];
    }

    float* sp = S + (((size_t)c * SSM_BATCH + b) * SSM_D + d) * SSM_N;
    #pragma unroll
    for (int i = 0; i < 4; ++i) *(float4v*)(sp + 4 * i) = h[i];
}

// ---------------- Combine: S_c -> carry_c = H_{c-1} (in place) ----------------
template <int NC, int L>
__global__ __launch_bounds__(256) void ssm_combine(
    const float* __restrict__ A_log, const float* __restrict__ log_dt,
    float* __restrict__ S)
{
    const int tid  = threadIdx.x;
    const int g    = tid & 3;
    const int dloc = tid >> 2;
    const int d    = blockIdx.x * 64 + dloc;
    const int b    = blockIdx.y;

    const float  dt  = expf(log_dt[d]);
    const float4v al = *(const float4v*)(A_log + d * SSM_N + 4 * g);
    const float4v dAL = exp4(((float)L * dt) * exp4(al));  // dA^L

    float* base = S + ((size_t)b * SSM_D + d) * SSM_N + 4 * g;
    const size_t cstride = (size_t)SSM_BATCH * SSM_D * SSM_N;

    float4v s[NC];
    #pragma unroll
    for (int c = 0; c < NC; ++c) s[c] = *(const float4v*)(base + c * cstride);

    float4v H = (float4v)0.f;
    #pragma unroll
    for (int c = 0; c < NC; ++c) {
        *(float4v*)(base + c * cstride) = H;   // carry-in for chunk c
        H = fma4(dAL, H, s[c]);
    }
}

// ---------------- Pass 2: rescan from carry, emit y ----------------
template <int L>
__global__ __launch_bounds__(256) void ssm_pass2(
    const float* __restrict__ x, const float* __restrict__ A_log,
    const float* __restrict__ Bm, const float* __restrict__ Cm,
    const float* __restrict__ log_dt, const float* __restrict__ S,
    float* __restrict__ out)
{
    const int tid = threadIdx.x;
    const int d   = blockIdx.x * 256 + tid;
    const int c   = blockIdx.y;
    const int b   = blockIdx.z;

    const float dt = expf(log_dt[d]);
    float4v dA[4], dB[4], cv[4], h[4];
    const float* sp = S + (((size_t)c * SSM_BATCH + b) * SSM_D + d) * SSM_N;
    #pragma unroll
    for (int i = 0; i < 4; ++i) {
        float4v al = *(const float4v*)(A_log + d * SSM_N + 4 * i);
        float4v bv = *(const float4v*)(Bm    + d * SSM_N + 4 * i);
        cv[i] = *(const float4v*)(Cm + d * SSM_N + 4 * i);
        dA[i] = exp4(dt * exp4(al));
        dB[i] = dt * bv;
        h[i]  = *(const float4v*)(sp + 4 * i);   // carry-in state
    }

    const float* xp = x   + ((size_t)b * SSM_SEQ + c * L) * SSM_D + d;
    float*       op = out + ((size_t)b * SSM_SEQ + c * L) * SSM_D + d;

    float xbuf[PF];
    #pragma unroll
    for (int i = 0; i < PF; ++i) xbuf[i] = xp[i * SSM_D];

    for (int t = 0; t < L; t += PF) {
        float xn[PF];
        if (t + PF < L) {
            #pragma unroll
            for (int i = 0; i < PF; ++i) xn[i] = xp[(t + PF + i) * SSM_D];
        }
        #pragma unroll
        for (int i = 0; i < PF; ++i) {
            const float xv = xbuf[i];
            #pragma unroll
            for (int j = 0; j < 4; ++j) h[j] = fma4(dA[j], h[j], dB[j] * xv);
            float4v pv = cv[0] * h[0];
            pv = fma4(cv[1], h[1], pv);
            pv = fma4(cv[2], h[2], pv);
            pv = fma4(cv[3], h[3], pv);
            op[(t + i) * SSM_D] = (pv.x + pv.y) + (pv.z + pv.w);
        }
        #pragma unroll
        for (int i = 0; i < PF; ++i) xbuf[i] = xn[i];
    }
}

// ---------------- Fallback (round-1 kernel, needs no workspace) ----------------
__global__ __launch_bounds__(256) void ssm_scan_fallback(
    const float* __restrict__ x, const float* __restrict__ A_log,
    const float* __restrict__ Bm, const float* __restrict__ Cm,
    const float* __restrict__ log_dt, float* __restrict__ out)
{
    const int tid  = threadIdx.x;
    const int sg   = tid & 3;
    const int dloc = tid >> 2;
    const int d    = blockIdx.x * 64 + dloc;
    const int b    = blockIdx.y;
    const int n0   = sg * 4;

    const float4 al = *(const float4*)(A_log + d * SSM_N + n0);
    const float4 bv = *(const float4*)(Bm    + d * SSM_N + n0);
    const float4 cvv = *(const float4*)(Cm   + d * SSM_N + n0);
    const float  dt = expf(log_dt[d]);

    const float dA0 = expf(dt * expf(al.x));
    const float dA1 = expf(dt * expf(al.y));
    const float dA2 = expf(dt * expf(al.z));
    const float dA3 = expf(dt * expf(al.w));
    const float dB0 = dt * bv.x, dB1 = dt * bv.y, dB2 = dt * bv.z, dB3 = dt * bv.w;

    const float* xp = x   + (size_t)b * SSM_SEQ * SSM_D + d;
    float*       op = out + (size_t)b * SSM_SEQ * SSM_D + d;

    float h0 = 0.f, h1 = 0.f, h2 = 0.f, h3 = 0.f;
    const bool writer = (sg == 0);

    float xbuf[16];
    #pragma unroll
    for (int i = 0; i < 16; ++i) xbuf[i] = xp[i * SSM_D];

    for (int t = 0; t < SSM_SEQ; t += 16) {
        float xn[16];
        if (t + 16 < SSM_SEQ) {
            #pragma unroll
            for (int i = 0; i < 16; ++i) xn[i] = xp[(t + 16 + i) * SSM_D];
        }
        #pragma unroll
        for (int i = 0; i < 16; ++i) {
            const float xv = xbuf[i];
            h0 = fmaf(dA0, h0, dB0 * xv);
            h1 = fmaf(dA1, h1, dB1 * xv);
            h2 = fmaf(dA2, h2, dB2 * xv);
            h3 = fmaf(dA3, h3, dB3 * xv);
            float p = cvv.x * h0;
            p = fmaf(cvv.y, h1, p);
            p = fmaf(cvv.z, h2, p);
            p = fmaf(cvv.w, h3, p);
            p += __shfl_xor(p, 1, 64);
            p += __shfl_xor(p, 2, 64);
            if (writer) op[(t + i) * SSM_D] = p;
        }
        #pragma unroll
        for (int i = 0; i < 16; ++i) xbuf[i] = xn[i];
    }
}

extern "C" void kernel_launch(void* const* d_in, const int* in_sizes, int n_in,
                              void* d_out, int out_size, void* d_ws, size_t ws_size,
                              hipStream_t stream) {
    const float* x      = (const float*)d_in[0];
    const float* A_log  = (const float*)d_in[1];
    const float* B      = (const float*)d_in[2];
    const float* C      = (const float*)d_in[3];
    const float* log_dt = (const float*)d_in[4];
    float* out = (float*)d_out;
    float* S   = (float*)d_ws;

    const size_t bytes_per_chunk =
        (size_t)SSM_BATCH * SSM_D * SSM_N * sizeof(float);   // 1 MiB

    if (ws_size >= 8 * bytes_per_chunk) {
        constexpr int NC = 8, L = SSM_SEQ / 8;               // L = 64
        dim3 gs(SSM_D / 256, NC, SSM_BATCH);
        ssm_pass1<L><<<gs, 256, 0, stream>>>(x, A_log, B, log_dt, S);
        dim3 gc(SSM_D / 64, SSM_BATCH);
        ssm_combine<NC, L><<<gc, 256, 0, stream>>>(A_log, log_dt, S);
        ssm_pass2<L><<<gs, 256, 0, stream>>>(x, A_log, B, C, log_dt, S, out);
    } else if (ws_size >= 4 * bytes_per_chunk) {
        constexpr int NC = 4, L = SSM_SEQ / 4;               // L = 128
        dim3 gs(SSM_D / 256, NC, SSM_BATCH);
        ssm_pass1<L><<<gs, 256, 0, stream>>>(x, A_log, B, log_dt, S);
        dim3 gc(SSM_D / 64, SSM_BATCH);
        ssm_combine<NC, L><<<gc, 256, 0, stream>>>(A_log, log_dt, S);
        ssm_pass2<L><<<gs, 256, 0, stream>>>(x, A_log, B, C, log_dt, S, out);
    } else {
        dim3 grid(SSM_D / 64, SSM_BATCH);
        ssm_scan_fallback<<<grid, 256, 0, stream>>>(x, A_log, B, C, log_dt, out);
    }
}

// Round 3
// 100.845 us; speedup vs baseline: 1.4611x; 1.1462x over previous
//
#include <hip/hip_runtime.h>
#include <math.h>

// SSM diagonal scan, single fused chunked-scan kernel.
//   reference: h_t = dA ⊙ h_{t-1} + dB·x_t ;  y_t = <C, h_t>
//   with dt=exp(log_dt), A=exp(A_log), dA=exp(dt*A), dB=dt*B  (all time-invariant).
//
// Algebra: h_n = dB_n·u_n where  u_n(t) = dA_n·u_n(t-1) + x_t  (x unscaled -> 1 FMA
// per state per step instead of mul+fma), and y_t = Σ_n dBC_n·u_n, dBC = dt·B·C.
// Carries combine in u-space with multiplier dA^L = exp(L·dt·A).
//
// Mapping: block = 512 thr = 32 d × 16 chunks(L=32); grid = (2048/32, 8) = 512 blocks
//   = 2 blocks/CU = 16 waves/CU = 4 waves/SIMD (launch_bounds(512,4) -> VGPR<=128).
// Each thread: load its chunk's 32 x values ONCE into registers (coalesced, huge MLP),
// local scan -> U_c, exchange via padded LDS, 128-thread serial combine -> carries,
// rescan pass 2 reusing the x still in registers (no second global read), write y.
// HBM = 33.5 MB read + 33.5 MB write -> ~10.7 us floor; VALU ~3.5 us (hidden).
// Round-2 lesson: 3 launches + global S round-trip + cross-launch x re-read cost ~35 us.

#define SSM_BATCH 8
#define SSM_SEQ 512
#define SSM_D 2048
#define SSM_N 16
#define NC 16          // chunks per sequence
#define CL 32          // chunk length = SEQ/NC
#define DPB 32         // d-channels per block

typedef float float4v __attribute__((ext_vector_type(4)));

static __device__ inline float4v fma4(float4v a, float4v b, float4v c) {
    return (float4v){fmaf(a.x, b.x, c.x), fmaf(a.y, b.y, c.y),
                     fmaf(a.z, b.z, c.z), fmaf(a.w, b.w, c.w)};
}
static __device__ inline float4v exp4(float4v v) {
    return (float4v){expf(v.x), expf(v.y), expf(v.z), expf(v.w)};
}

__global__ __launch_bounds__(512, 4) void ssm_fused(
    const float* __restrict__ x, const float* __restrict__ A_log,
    const float* __restrict__ Bm, const float* __restrict__ Cm,
    const float* __restrict__ log_dt, float* __restrict__ out)
{
    const int tid = threadIdx.x;
    const int dl  = tid & (DPB - 1);   // channel within block
    const int c   = tid >> 5;          // chunk index 0..15
    const int d   = blockIdx.x * DPB + dl;
    const int b   = blockIdx.y;

    // [DPB*4 chains][stride 17 float4] — +1 pad spreads b128 bank starts.
    __shared__ float4v S4[DPB * 4 * 17];   // 34816 B -> 2 blocks/CU fits 160 KB

    // ---- issue all 32 x loads first (independent of the exp chain) ----
    const size_t xoff = ((size_t)b * SSM_SEQ + c * CL) * SSM_D + d;
    const float* xp = x + xoff;
    float xb[CL];
    #pragma unroll
    for (int t = 0; t < CL; ++t) xb[t] = xp[(size_t)t * SSM_D];

    // ---- per-channel params (exp chain overlaps the loads) ----
    const float dt = expf(log_dt[d]);
    float4v dA[4];
    #pragma unroll
    for (int j = 0; j < 4; ++j) {
        float4v al = *(const float4v*)(A_log + d * SSM_N + 4 * j);
        dA[j] = exp4(dt * exp4(al));
    }

    // ---- pass 1: chunk-local scan from 0 -> U_c ----
    float4v u[4];
    #pragma unroll
    for (int j = 0; j < 4; ++j) u[j] = (float4v)0.f;
    #pragma unroll
    for (int t = 0; t < CL; ++t) {
        const float xv = xb[t];
        const float4v xs = {xv, xv, xv, xv};
        #pragma unroll
        for (int j = 0; j < 4; ++j) u[j] = fma4(dA[j], u[j], xs);
    }
    #pragma unroll
    for (int j = 0; j < 4; ++j) S4[(dl * 4 + j) * 17 + c] = u[j];
    __syncthreads();

    // ---- combine: 128 chains (32 d × 4 state-groups), serial over 16 chunks ----
    if (tid < DPB * 4) {
        const int cdl = tid >> 2, g = tid & 3;
        const int dd  = blockIdx.x * DPB + cdl;
        const float dt2 = expf(log_dt[dd]);
        float4v al = *(const float4v*)(A_log + dd * SSM_N + 4 * g);
        float4v dAL = exp4(((float)CL * dt2) * exp4(al));   // dA^L
        float4v H = (float4v)0.f;
        float4v* row = &S4[(cdl * 4 + g) * 17];
        #pragma unroll
        for (int cc = 0; cc < NC; ++cc) {
            float4v s = row[cc];
            row[cc] = H;               // exclusive prefix = carry-in for chunk cc
            H = fma4(dAL, H, s);
        }
    }
    __syncthreads();

    // ---- pass 2: rescan from carry, reuse x in registers, emit y ----
    float4v dBC[4];
    #pragma unroll
    for (int j = 0; j < 4; ++j) {
        float4v bv = *(const float4v*)(Bm + d * SSM_N + 4 * j);
        float4v cv = *(const float4v*)(Cm + d * SSM_N + 4 * j);
        dBC[j] = (dt * bv) * cv;
        u[j] = S4[(dl * 4 + j) * 17 + c];
    }

    float* op = out + xoff;
    #pragma unroll
    for (int t = 0; t < CL; ++t) {
        const float xv = xb[t];
        const float4v xs = {xv, xv, xv, xv};
        #pragma unroll
        for (int j = 0; j < 4; ++j) u[j] = fma4(dA[j], u[j], xs);
        float4v p = dBC[0] * u[0];
        p = fma4(dBC[1], u[1], p);
        p = fma4(dBC[2], u[2], p);
        p = fma4(dBC[3], u[3], p);
        op[(size_t)t * SSM_D] = (p.x + p.y) + (p.z + p.w);
    }
}

extern "C" void kernel_launch(void* const* d_in, const int* in_sizes, int n_in,
                              void* d_out, int out_size, void* d_ws, size_t ws_size,
                              hipStream_t stream) {
    const float* x      = (const float*)d_in[0];
    const float* A_log  = (const float*)d_in[1];
    const float* B      = (const float*)d_in[2];
    const float* C      = (const float*)d_in[3];
    const float* log_dt = (const float*)d_in[4];
    float* out = (float*)d_out;

    dim3 grid(SSM_D / DPB, SSM_BATCH);   // 64 x 8 = 512 blocks, 2 blocks/CU
    ssm_fused<<<grid, DPB * NC, 0, stream>>>(x, A_log, B, C, log_dt, out);
}